// Round 9
// baseline (124.870 us; speedup 1.0000x reference)
//
#include <hip/hip_runtime.h>
#include <stdint.h>
#include <algorithm>
#include <numeric>

#define V_N    4096
#define B_N    4
#define C_N    128
#define POOL_N 1024   // V_N / POOLING_RATE
#define K_NBR  4
#define FLAG_MAGIC 0x600DF00D

// ---------------- Threefry-2x32 (20 rounds), exactly as JAX lowers it ----
// Host-only: permutation is input-independent, computed on CPU each call
// (deterministic), shipped as a 2 KB kernarg struct.
static inline void tf2x32(uint32_t k0, uint32_t k1, uint32_t x0, uint32_t x1,
                          uint32_t& o0, uint32_t& o1) {
  uint32_t ks[3] = {k0, k1, k0 ^ k1 ^ 0x1BD11BDAu};
  const int R[5][4] = {{13,15,26,6},{17,29,16,24},{13,15,26,6},{17,29,16,24},{13,15,26,6}};
  x0 += ks[0]; x1 += ks[1];
  for (int g = 0; g < 5; ++g) {
    for (int r = 0; r < 4; ++r) {
      x0 += x1;
      const int rot = R[g][r];
      x1 = (x1 << rot) | (x1 >> (32 - rot));
      x1 ^= x0;
    }
    x0 += ks[(g + 1) % 3];
    x1 += ks[(g + 2) % 3] + (uint32_t)(g + 1);
  }
  o0 = x0; o1 = x1;
}

struct SampleIdx { unsigned short v[POOL_N]; };   // 2048 B kernarg payload

__device__ __forceinline__ bool lexlt(float d1, int i1, float d2, int i2) {
  return d1 < d2 || (d1 == d2 && i1 < i2);
}
__device__ __forceinline__ void ce(float& da, int& ia, float& db, int& ib) {
  if (!lexlt(da, ia, db, ib)) {
    float td = da; da = db; db = td;
    int   ti = ia; ia = ib; ib = ti;
  }
}

// kNN body shared by fused and fallback kernels. Replicates reference fp32
// rounding exactly (validated absmax=0 across rounds 1-8):
//   quad = (x*x+y*y)+z*z ; inner = fmaf(z,z',fmaf(y,y',x*x'))
//   dist = ((-2*inner)+quad_m)+quad_n ; lexicographic (dist,idx) top-4, no self.
#define KNN_BODY(SV4, SV, QV, BD0,BI0,BD1,BI1,BD2,BI2,BD3,BI3, QX,QY,QZ,QQ)   \
  const float QX = SV[3 * QV], QY = SV[3 * QV + 1], QZ = SV[3 * QV + 2];      \
  const float QQ = __fadd_rn(__fadd_rn(__fmul_rn(QX, QX), __fmul_rn(QY, QY)), \
                             __fmul_rn(QZ, QZ));                              \
  float BD0 = 1e30f, BD1 = 1e30f, BD2 = 1e30f, BD3 = 1e30f;                   \
  int   BI0 = -1, BI1 = -1, BI2 = -1, BI3 = -1;                               \
  _Pragma("unroll 4")                                                         \
  for (int i_ = 0; i_ < 16; ++i_) {                                           \
    const int base_ = lane + 64 * i_;                                         \
    const float4 c0_ = SV4[3 * base_ + 0];                                    \
    const float4 c1_ = SV4[3 * base_ + 1];                                    \
    const float4 c2_ = SV4[3 * base_ + 2];                                    \
    const int m0_ = 4 * base_;                                                \
    EVAL(c0_.x, c0_.y, c0_.z, m0_ + 0);                                       \
    EVAL(c0_.w, c1_.x, c1_.y, m0_ + 1);                                       \
    EVAL(c1_.z, c1_.w, c2_.x, m0_ + 2);                                       \
    EVAL(c2_.y, c2_.z, c2_.w, m0_ + 3);                                       \
  }                                                                           \
  _Pragma("unroll")                                                           \
  for (int off = 1; off <= 32; off <<= 1) {                                   \
    const float e0 = __shfl_xor(BD0, off), e1 = __shfl_xor(BD1, off);         \
    const float e2 = __shfl_xor(BD2, off), e3 = __shfl_xor(BD3, off);         \
    const int   f0 = __shfl_xor(BI0, off), f1 = __shfl_xor(BI1, off);         \
    const int   f2 = __shfl_xor(BI2, off), f3 = __shfl_xor(BI3, off);         \
    const bool c0 = lexlt(BD0, BI0, e3, f3); BD0 = c0 ? BD0 : e3; BI0 = c0 ? BI0 : f3; \
    const bool c1 = lexlt(BD1, BI1, e2, f2); BD1 = c1 ? BD1 : e2; BI1 = c1 ? BI1 : f2; \
    const bool c2 = lexlt(BD2, BI2, e1, f1); BD2 = c2 ? BD2 : e1; BI2 = c2 ? BI2 : f1; \
    const bool c3 = lexlt(BD3, BI3, e0, f0); BD3 = c3 ? BD3 : e0; BI3 = c3 ? BI3 : f0; \
    ce(BD0, BI0, BD2, BI2); ce(BD1, BI1, BD3, BI3);                           \
    ce(BD0, BI0, BD1, BI1); ce(BD2, BI2, BD3, BI3);                           \
  }

#define EVAL(X, Y, Z, MC)                                                     \
  do {                                                                        \
    const float x_ = (X), y_ = (Y), z_ = (Z);                                 \
    const int mc_ = (MC);                                                     \
    const float qm_ = __fadd_rn(__fadd_rn(__fmul_rn(x_, x_),                  \
                                          __fmul_rn(y_, y_)),                 \
                                __fmul_rn(z_, z_));                           \
    const float in_ = __fmaf_rn(qz, z_, __fmaf_rn(qy, y_, __fmul_rn(qx, x_)));\
    const float dist = __fadd_rn(__fmaf_rn(-2.0f, in_, qm_), qq);             \
    if (mc_ != qv && dist < bd3) {                                            \
      if (dist < bd2) {                                                       \
        bd3 = bd2; bi3 = bi2;                                                 \
        if (dist < bd1) {                                                     \
          bd2 = bd1; bi2 = bi1;                                               \
          if (dist < bd0) { bd1 = bd0; bi1 = bi0; bd0 = dist; bi0 = mc_; }    \
          else            { bd1 = dist; bi1 = mc_; }                          \
        } else { bd2 = dist; bi2 = mc_; }                                     \
      } else { bd3 = dist; bi3 = mc_; }                                       \
    }                                                                         \
  } while (0)

// ---------------- Fused cooperative kernel: knn + msg-pass + pool ---------
// Block w: knn for queries [8(w&127)..) of batch w>>7, then pool for
// (b,c) = (w>>7, w&127). One-way release/acquire handoff via flags (no
// grid.sync). fm slice reg-staged before knn so HBM latency overlaps VALU.
__global__ __launch_bounds__(512, 4)
void fused_kernel(const float* __restrict__ verts, const float* __restrict__ fm,
                  const SampleIdx si, int* __restrict__ nbr,
                  unsigned int* __restrict__ flags, float* __restrict__ out) {
  __shared__ float4 sv4[V_N * 3 / 4];           // 48 KB: verts xyz, then fm slice
  const float* sv = (const float*)sv4;
  const int tid = threadIdx.x;
  const int w = blockIdx.x;                     // 0..511
  const int b = w >> 7;
  const int g = w & 127;                        // query group == channel

  const float4* vb4 = (const float4*)(verts + (size_t)b * V_N * 3);
#pragma unroll
  for (int i = 0; i < 6; ++i)
    sv4[tid + 512 * i] = vb4[tid + 512 * i];

  // reg-stage this block's fm slice early: loads fly during the knn compute
  const float4* fsrc = (const float4*)(fm + (size_t)w * V_N * 3);
  float4 st0 = fsrc[tid + 512 * 0], st1 = fsrc[tid + 512 * 1];
  float4 st2 = fsrc[tid + 512 * 2], st3 = fsrc[tid + 512 * 3];
  float4 st4 = fsrc[tid + 512 * 4], st5 = fsrc[tid + 512 * 5];
  __syncthreads();

  // ---- Phase 1: kNN (one query per wave), bit-identical to round 7 -------
  const int lane = tid & 63;
  const int wv   = tid >> 6;
  const int qid  = g * 8 + wv;
  const int qv   = si.v[qid];
  KNN_BODY(sv4, sv, qv, bd0,bi0,bd1,bi1,bd2,bi2,bd3,bi3, qx,qy,qz,qq)

  if (lane == 0) {
    ((int4*)nbr)[b * POOL_N + qid] = make_int4(bi0, bi1, bi2, bi3);
    float* ov = out + ((size_t)b * POOL_N + qid) * 3;   // fused vertices_pool
    ov[0] = qx; ov[1] = qy; ov[2] = qz;
  }
  __syncthreads();   // drains nbr stores (vmcnt) + all waves done with verts LDS

  // overwrite LDS with fm slice
  sv4[tid + 512 * 0] = st0; sv4[tid + 512 * 1] = st1;
  sv4[tid + 512 * 2] = st2; sv4[tid + 512 * 3] = st3;
  sv4[tid + 512 * 4] = st4; sv4[tid + 512 * 5] = st5;

  // release: nbr visible at device scope, then publish flag
  if (tid == 0) {
    __threadfence();
    __hip_atomic_store(&flags[w], (unsigned int)FLAG_MAGIC,
                       __ATOMIC_RELAXED, __HIP_MEMORY_SCOPE_AGENT);
  }
  // acquire: wait for all 128 producer blocks of this batch
  if (tid < 128) {
    while (__hip_atomic_load(&flags[b * 128 + tid],
                             __ATOMIC_RELAXED, __HIP_MEMORY_SCOPE_AGENT)
           != (unsigned int)FLAG_MAGIC)
      __builtin_amdgcn_s_sleep(8);
  }
  __syncthreads();
  __threadfence();

  // ---- Phase 2: feature max-pool for channel slice (b, c=g) from LDS -----
  const float* sf = sv;
  float* outF = out + (size_t)B_N * POOL_N * 3 + (size_t)w * POOL_N * 3;
  const int4* nb4 = (const int4*)nbr + b * POOL_N;
#pragma unroll
  for (int p = 0; p < 2; ++p) {
    const int j = tid * 2 + p;
    const int4 nb = nb4[j];
    const float* p0 = sf + nb.x * 3;
    const float* p1 = sf + nb.y * 3;
    const float* p2 = sf + nb.z * 3;
    const float* p3 = sf + nb.w * 3;
    const float r0 = fmaxf(fmaxf(p0[0], p1[0]), fmaxf(p2[0], p3[0]));
    const float r1 = fmaxf(fmaxf(p0[1], p1[1]), fmaxf(p2[1], p3[1]));
    const float r2 = fmaxf(fmaxf(p0[2], p1[2]), fmaxf(p2[2], p3[2]));
    float* dst = outF + (size_t)j * 3;
    dst[0] = r0; dst[1] = r1; dst[2] = r2;
  }
}

// ---------------- Fallback: round-7 two-kernel path (validated) -----------
__global__ __launch_bounds__(512) void knn_kernel(const float* __restrict__ verts,
                                                  const SampleIdx si,
                                                  int* __restrict__ nbr,
                                                  float* __restrict__ outV) {
  __shared__ float4 sv4[V_N * 3 / 4];
  const float* sv = (const float*)sv4;
  const int tid = threadIdx.x;
  const int b = blockIdx.y;
  const float4* vb4 = (const float4*)(verts + (size_t)b * V_N * 3);
#pragma unroll
  for (int w = 0; w < 6; ++w)
    sv4[tid + 512 * w] = vb4[tid + 512 * w];
  __syncthreads();

  const int lane = tid & 63;
  const int wv   = tid >> 6;
  const int qid  = blockIdx.x * 8 + wv;
  const int qv   = si.v[qid];
  KNN_BODY(sv4, sv, qv, bd0,bi0,bd1,bi1,bd2,bi2,bd3,bi3, qx,qy,qz,qq)

  if (lane == 0) {
    ((int4*)nbr)[b * POOL_N + qid] = make_int4(bi0, bi1, bi2, bi3);
    float* ov = outV + ((size_t)b * POOL_N + qid) * 3;
    ov[0] = qx; ov[1] = qy; ov[2] = qz;
  }
}

__global__ __launch_bounds__(256) void pool_kernel(const float* __restrict__ fm,
                                                   const int* __restrict__ nbr,
                                                   float* __restrict__ outF) {
  __shared__ float4 sf4[V_N * 3 / 4];
  const float* sf = (const float*)sf4;
  const int tid = threadIdx.x;
  const int bc = blockIdx.x;
  const int b  = bc >> 7;
  const float4* src = (const float4*)(fm + (size_t)bc * V_N * 3);
#pragma unroll
  for (int w = 0; w < 12; ++w)
    sf4[tid + 256 * w] = src[tid + 256 * w];
  __syncthreads();

  const int j0 = tid * 4;
  const int4* nb4 = (const int4*)(nbr) + b * POOL_N + j0;
  float r[12];
#pragma unroll
  for (int k = 0; k < 4; ++k) {
    const int4 nb = nb4[k];
    const float* p0 = sf + nb.x * 3; const float* p1 = sf + nb.y * 3;
    const float* p2 = sf + nb.z * 3; const float* p3 = sf + nb.w * 3;
    r[k * 3 + 0] = fmaxf(fmaxf(p0[0], p1[0]), fmaxf(p2[0], p3[0]));
    r[k * 3 + 1] = fmaxf(fmaxf(p0[1], p1[1]), fmaxf(p2[1], p3[1]));
    r[k * 3 + 2] = fmaxf(fmaxf(p0[2], p1[2]), fmaxf(p2[2], p3[2]));
  }
  float4* dst = (float4*)(outF + (size_t)bc * POOL_N * 3 + (size_t)j0 * 3);
  dst[0] = make_float4(r[0], r[1], r[2], r[3]);
  dst[1] = make_float4(r[4], r[5], r[6], r[7]);
  dst[2] = make_float4(r[8], r[9], r[10], r[11]);
}

extern "C" void kernel_launch(void* const* d_in, const int* in_sizes, int n_in,
                              void* d_out, int out_size, void* d_ws, size_t ws_size,
                              hipStream_t stream) {
  const float* verts = (const float*)d_in[0];   // (4, 4096, 3) f32
  const float* fm    = (const float*)d_in[1];   // (4, 128, 4096, 3) f32
  float* out = (float*)d_out;                   // 12288 + 1572864 f32
  int* nbr = (int*)d_ws;                        // [4*1024*4], 16-B aligned
  unsigned int* flags = (unsigned int*)(nbr + B_N * POOL_N * 4);  // [512]

  // ---- Host-side permutation (input-independent, recomputed every call) ---
  uint32_t k0 = 0u, k1 = 42u, sub0[2], sub1[2];
  for (int r = 0; r < 2; ++r) {
    uint32_t n0, n1, s0, s1;
    tf2x32(k0, k1, 0u, 0u, n0, n1);
    tf2x32(k0, k1, 0u, 1u, s0, s1);
    sub0[r] = s0; sub1[r] = s1; k0 = n0; k1 = n1;
  }
  static thread_local uint32_t b1[V_N], b2[V_N];
  static thread_local int ord1[V_N], ord2[V_N];
  for (int i = 0; i < V_N; ++i) {
    uint32_t h, l;
    tf2x32(sub0[0], sub1[0], 0u, (uint32_t)i, h, l); b1[i] = h ^ l;
    tf2x32(sub0[1], sub1[1], 0u, (uint32_t)i, h, l); b2[i] = h ^ l;
  }
  std::iota(ord1, ord1 + V_N, 0);
  std::stable_sort(ord1, ord1 + V_N, [](int a, int b_) { return b1[a] < b1[b_]; });
  std::iota(ord2, ord2 + V_N, 0);
  std::stable_sort(ord2, ord2 + V_N, [](int a, int b_) { return b2[a] < b2[b_]; });
  SampleIdx si;
  for (int j = 0; j < POOL_N; ++j)
    si.v[j] = (unsigned short)ord1[ord2[j]];    // perm[j] = v1[ord2[j]]

  void* args[] = {(void*)&verts, (void*)&fm, (void*)&si,
                  (void*)&nbr, (void*)&flags, (void*)&out};
  hipError_t err = hipLaunchCooperativeKernel((const void*)fused_kernel,
                                              dim3(512), dim3(512),
                                              args, 0, stream);
  if (err != hipSuccess) {
    // deterministic fallback: validated round-7 two-kernel path
    knn_kernel<<<dim3(POOL_N / 8, B_N), 512, 0, stream>>>(verts, si, nbr, out);
    pool_kernel<<<B_N * C_N, 256, 0, stream>>>(fm, nbr, out + B_N * POOL_N * 3);
  }
}

// Round 10
// 26.494 us; speedup vs baseline: 4.7132x; 4.7132x over previous
//
#include <hip/hip_runtime.h>
#include <stdint.h>
#include <algorithm>
#include <numeric>

#define V_N    4096
#define B_N    4
#define C_N    128
#define POOL_N 1024   // V_N / POOLING_RATE
#define K_NBR  4

// ---------------- Threefry-2x32 (20 rounds), exactly as JAX lowers it ----
// Host-only: permutation is input-independent, computed on CPU each call
// (deterministic), shipped as a 2 KB kernarg struct.
static inline void tf2x32(uint32_t k0, uint32_t k1, uint32_t x0, uint32_t x1,
                          uint32_t& o0, uint32_t& o1) {
  uint32_t ks[3] = {k0, k1, k0 ^ k1 ^ 0x1BD11BDAu};
  const int R[5][4] = {{13,15,26,6},{17,29,16,24},{13,15,26,6},{17,29,16,24},{13,15,26,6}};
  x0 += ks[0]; x1 += ks[1];
  for (int g = 0; g < 5; ++g) {
    for (int r = 0; r < 4; ++r) {
      x0 += x1;
      const int rot = R[g][r];
      x1 = (x1 << rot) | (x1 >> (32 - rot));
      x1 ^= x0;
    }
    x0 += ks[(g + 1) % 3];
    x1 += ks[(g + 2) % 3] + (uint32_t)(g + 1);
  }
  o0 = x0; o1 = x1;
}

struct SampleIdx { unsigned short v[POOL_N]; };   // 2048 B kernarg payload

__device__ __forceinline__ bool lexlt(float d1, int i1, float d2, int i2) {
  return d1 < d2 || (d1 == d2 && i1 < i2);
}
__device__ __forceinline__ void ce(float& da, int& ia, float& db, int& ib) {
  if (!lexlt(da, ia, db, ib)) {
    float td = da; da = db; db = td;
    int   ti = ia; ia = ib; ib = ti;
  }
}

// slot swizzle (involution): spreads 128B-stride LDS writes across bank
// groups; read base sw(lane) gives candidate index exactly lane+64i.
__device__ __forceinline__ int sw(int v) {
  return (v & ~7) | ((v & 7) ^ ((v >> 3) & 7));
}

// ---------------- Kernel 1: kNN, one query per WAVE + shuffle merge -------
// LDS holds {x, y, z, quad} per vertex (quad precomputed ONCE with the exact
// reference expression -> bit-identical dist):
//   quad = (x*x+y*y)+z*z ; inner = fmaf(z,z',fmaf(y,y',x*x'))
//   dist = ((-2*inner)+quad_m)+quad_n
// Selection: lexicographic (dist, idx) top-4 excluding self == top_k[1:],
// scanned in ascending m per lane (strict-< insertion keeps tie-break).
__global__ __launch_bounds__(512) void knn_kernel(const float* __restrict__ verts,
                                                  const SampleIdx si,
                                                  int* __restrict__ nbr,
                                                  float* __restrict__ outV) {
  __shared__ float4 sq4[V_N];                   // 64 KB {x,y,z,quad}
  const int tid = threadIdx.x;
  const int b = blockIdx.y;

  // stage 8 vertices/thread (96 B contiguous), compute quad, swizzled write
  {
    const float4* src = (const float4*)(verts + (size_t)b * V_N * 3) + 6 * tid;
    float v[24];
    *(float4*)&v[0]  = src[0]; *(float4*)&v[4]  = src[1];
    *(float4*)&v[8]  = src[2]; *(float4*)&v[12] = src[3];
    *(float4*)&v[16] = src[4]; *(float4*)&v[20] = src[5];
    const int h = tid & 7;                      // ((8t+k)>>3)&7 == t&7
#pragma unroll
    for (int k = 0; k < 8; ++k) {
      const float x = v[3 * k], y = v[3 * k + 1], z = v[3 * k + 2];
      const float qm = __fadd_rn(__fadd_rn(__fmul_rn(x, x), __fmul_rn(y, y)),
                                 __fmul_rn(z, z));
      sq4[8 * tid + (k ^ h)] = make_float4(x, y, z, qm);
    }
  }
  __syncthreads();

  const int lane = tid & 63;
  const int wv   = tid >> 6;                    // wave id 0..7 = query slot
  const int qid  = blockIdx.x * 8 + wv;         // 0..1023 output slot
  const int qv   = si.v[qid];                   // sampled vertex (kernarg)
  const float4 q = sq4[sw(qv)];
  const float qx = q.x, qy = q.y, qz = q.z, qq = q.w;

  float bd0 = 1e30f, bd1 = 1e30f, bd2 = 1e30f, bd3 = 1e30f;
  int   bi0 = -1, bi1 = -1, bi2 = -1, bi3 = -1;

  const float4* sbase = sq4 + sw(lane);         // per-lane const base
#pragma unroll
  for (int i = 0; i < 64; ++i) {
    const float4 c = sbase[64 * i];             // ds_read_b128 offset:1024*i
    const int mc = lane + 64 * i;               // vertex at swizzled slot
    const float inner = __fmaf_rn(qz, c.z, __fmaf_rn(qy, c.y, __fmul_rn(qx, c.x)));
    const float dist = __fadd_rn(__fmaf_rn(-2.0f, inner, c.w), qq);
    if (mc != qv && dist < bd3) {
      if (dist < bd2) {
        bd3 = bd2; bi3 = bi2;
        if (dist < bd1) {
          bd2 = bd1; bi2 = bi1;
          if (dist < bd0) { bd1 = bd0; bi1 = bi0; bd0 = dist; bi0 = mc; }
          else            { bd1 = dist; bi1 = mc; }
        } else { bd2 = dist; bi2 = mc; }
      } else { bd3 = dist; bi3 = mc; }
    }
  }

  // 6-stage butterfly: merge two sorted 4-lists -> sorted top-4 (bitonic).
#pragma unroll
  for (int off = 1; off <= 32; off <<= 1) {
    const float e0 = __shfl_xor(bd0, off), e1 = __shfl_xor(bd1, off);
    const float e2 = __shfl_xor(bd2, off), e3 = __shfl_xor(bd3, off);
    const int   f0 = __shfl_xor(bi0, off), f1 = __shfl_xor(bi1, off);
    const int   f2 = __shfl_xor(bi2, off), f3 = __shfl_xor(bi3, off);
    const bool c0 = lexlt(bd0, bi0, e3, f3); bd0 = c0 ? bd0 : e3; bi0 = c0 ? bi0 : f3;
    const bool c1 = lexlt(bd1, bi1, e2, f2); bd1 = c1 ? bd1 : e2; bi1 = c1 ? bi1 : f2;
    const bool c2 = lexlt(bd2, bi2, e1, f1); bd2 = c2 ? bd2 : e1; bi2 = c2 ? bi2 : f1;
    const bool c3 = lexlt(bd3, bi3, e0, f0); bd3 = c3 ? bd3 : e0; bi3 = c3 ? bi3 : f0;
    ce(bd0, bi0, bd2, bi2); ce(bd1, bi1, bd3, bi3);
    ce(bd0, bi0, bd1, bi1); ce(bd2, bi2, bd3, bi3);
  }

  if (lane == 0) {
    ((int4*)nbr)[b * POOL_N + qid] = make_int4(bi0, bi1, bi2, bi3);
    float* ov = outV + ((size_t)b * POOL_N + qid) * 3;   // fused vertices_pool
    ov[0] = qx; ov[1] = qy; ov[2] = qz;
  }
}

// ---------------- Kernel 2: feature max-pool, LDS-staged (b,c) slice ------
// One block per (b,c): coalesced float4 read of the 48 KB slice into LDS
// (512 threads = 16 waves/CU for HBM latency hiding), gather+max from LDS,
// contiguous float2 stores. Exact max of 4 floats.
__global__ __launch_bounds__(512) void pool_kernel(const float* __restrict__ fm,
                                                   const int* __restrict__ nbr,
                                                   float* __restrict__ outF) {
  __shared__ float4 sf4[V_N * 3 / 4];           // 48 KB
  const float* sf = (const float*)sf4;
  const int tid = threadIdx.x;
  const int bc = blockIdx.x;                    // 0..511 = b*128 + c
  const int b  = bc >> 7;
  const float4* src = (const float4*)(fm + (size_t)bc * V_N * 3);
#pragma unroll
  for (int w = 0; w < 6; ++w)
    sf4[tid + 512 * w] = src[tid + 512 * w];
  __syncthreads();

  const int j0 = tid * 2;                       // 2 outputs per thread
  const int4* nb4 = (const int4*)(nbr) + b * POOL_N + j0;
  const int4 n0 = nb4[0], n1 = nb4[1];

  const float* a0 = sf + n0.x * 3; const float* a1 = sf + n0.y * 3;
  const float* a2 = sf + n0.z * 3; const float* a3 = sf + n0.w * 3;
  const float r0 = fmaxf(fmaxf(a0[0], a1[0]), fmaxf(a2[0], a3[0]));
  const float r1 = fmaxf(fmaxf(a0[1], a1[1]), fmaxf(a2[1], a3[1]));
  const float r2 = fmaxf(fmaxf(a0[2], a1[2]), fmaxf(a2[2], a3[2]));

  const float* b0 = sf + n1.x * 3; const float* b1 = sf + n1.y * 3;
  const float* b2 = sf + n1.z * 3; const float* b3 = sf + n1.w * 3;
  const float r3 = fmaxf(fmaxf(b0[0], b1[0]), fmaxf(b2[0], b3[0]));
  const float r4 = fmaxf(fmaxf(b0[1], b1[1]), fmaxf(b2[1], b3[1]));
  const float r5 = fmaxf(fmaxf(b0[2], b1[2]), fmaxf(b2[2], b3[2]));

  float2* dst = (float2*)(outF + (size_t)bc * POOL_N * 3) + 3 * tid;
  dst[0] = make_float2(r0, r1);
  dst[1] = make_float2(r2, r3);
  dst[2] = make_float2(r4, r5);
}

extern "C" void kernel_launch(void* const* d_in, const int* in_sizes, int n_in,
                              void* d_out, int out_size, void* d_ws, size_t ws_size,
                              hipStream_t stream) {
  const float* verts = (const float*)d_in[0];   // (4, 4096, 3) f32
  const float* fm    = (const float*)d_in[1];   // (4, 128, 4096, 3) f32
  float* out = (float*)d_out;                   // 12288 + 1572864 f32
  int* nbr = (int*)d_ws;                        // [4*1024*4], 16-B aligned

  // ---- Host-side permutation (input-independent, recomputed every call) ---
  // key(42) = (0, 42); 2 rounds of foldlike split -> random_bits -> stable
  // sort; identical rank semantics to the device version validated absmax=0.
  uint32_t k0 = 0u, k1 = 42u, sub0[2], sub1[2];
  for (int r = 0; r < 2; ++r) {
    uint32_t n0, n1, s0, s1;
    tf2x32(k0, k1, 0u, 0u, n0, n1);
    tf2x32(k0, k1, 0u, 1u, s0, s1);
    sub0[r] = s0; sub1[r] = s1; k0 = n0; k1 = n1;
  }
  static thread_local uint32_t b1[V_N], b2[V_N];
  static thread_local int ord1[V_N], ord2[V_N];
  for (int i = 0; i < V_N; ++i) {
    uint32_t h, l;
    tf2x32(sub0[0], sub1[0], 0u, (uint32_t)i, h, l); b1[i] = h ^ l;
    tf2x32(sub0[1], sub1[1], 0u, (uint32_t)i, h, l); b2[i] = h ^ l;
  }
  std::iota(ord1, ord1 + V_N, 0);
  std::stable_sort(ord1, ord1 + V_N, [](int a, int b_) { return b1[a] < b1[b_]; });
  std::iota(ord2, ord2 + V_N, 0);
  std::stable_sort(ord2, ord2 + V_N, [](int a, int b_) { return b2[a] < b2[b_]; });
  SampleIdx si;
  for (int j = 0; j < POOL_N; ++j)
    si.v[j] = (unsigned short)ord1[ord2[j]];    // perm[j] = v1[ord2[j]]

  knn_kernel<<<dim3(POOL_N / 8, B_N), 512, 0, stream>>>(verts, si, nbr, out);
  pool_kernel<<<B_N * C_N, 512, 0, stream>>>(fm, nbr, out + B_N * POOL_N * 3);
}